// Round 1
// baseline (94.655 us; speedup 1.0000x reference)
//
#include <hip/hip_runtime.h>

// Nadaraya-Watson kernel regression, one block per row.
// out[i] = sum_j softmax_j(-0.5*((q[i]-K[i,j])*w)^2) * V[i,j]
// All exponents <= 0 so exp() <= 1: no max-subtraction needed -> single pass.
__global__ __launch_bounds__(256) void nw_regression_kernel(
    const float* __restrict__ q,
    const float* __restrict__ keys,
    const float* __restrict__ values,
    const float* __restrict__ w,
    float* __restrict__ out,
    int K)
{
    const int row = blockIdx.x;
    const float qi = q[row];
    const float wv = w[0];

    const float4* __restrict__ krow =
        reinterpret_cast<const float4*>(keys + (size_t)row * (size_t)K);
    const float4* __restrict__ vrow =
        reinterpret_cast<const float4*>(values + (size_t)row * (size_t)K);

    const int nvec = K >> 2;  // K assumed multiple of 4 (8192)

    float sum_e = 0.0f;   // sum of exp terms
    float sum_ev = 0.0f;  // sum of exp * value

    for (int idx = threadIdx.x; idx < nvec; idx += 256) {
        float4 kv = krow[idx];
        float4 vv = vrow[idx];

        float d0 = (qi - kv.x) * wv;
        float d1 = (qi - kv.y) * wv;
        float d2 = (qi - kv.z) * wv;
        float d3 = (qi - kv.w) * wv;

        float e0 = __expf(-0.5f * d0 * d0);
        float e1 = __expf(-0.5f * d1 * d1);
        float e2 = __expf(-0.5f * d2 * d2);
        float e3 = __expf(-0.5f * d3 * d3);

        sum_e  += (e0 + e1) + (e2 + e3);
        sum_ev += (e0 * vv.x + e1 * vv.y) + (e2 * vv.z + e3 * vv.w);
    }

    // Wave-level butterfly reduce (wave = 64 lanes on CDNA).
    #pragma unroll
    for (int off = 32; off > 0; off >>= 1) {
        sum_e  += __shfl_down(sum_e, off, 64);
        sum_ev += __shfl_down(sum_ev, off, 64);
    }

    __shared__ float s_e[4];
    __shared__ float s_ev[4];
    const int wid  = threadIdx.x >> 6;
    const int lane = threadIdx.x & 63;
    if (lane == 0) {
        s_e[wid]  = sum_e;
        s_ev[wid] = sum_ev;
    }
    __syncthreads();

    if (threadIdx.x == 0) {
        float te  = (s_e[0] + s_e[1]) + (s_e[2] + s_e[3]);
        float tev = (s_ev[0] + s_ev[1]) + (s_ev[2] + s_ev[3]);
        out[row] = tev / te;
    }
}

extern "C" void kernel_launch(void* const* d_in, const int* in_sizes, int n_in,
                              void* d_out, int out_size, void* d_ws, size_t ws_size,
                              hipStream_t stream) {
    const float* q      = (const float*)d_in[0];
    const float* keys   = (const float*)d_in[1];
    const float* values = (const float*)d_in[2];
    const float* w      = (const float*)d_in[3];
    float* out = (float*)d_out;

    const int N = in_sizes[0];
    const int K = in_sizes[1] / N;

    nw_regression_kernel<<<N, 256, 0, stream>>>(q, keys, values, w, out, K);
}

// Round 2
// 82.948 us; speedup vs baseline: 1.1411x; 1.1411x over previous
//
#include <hip/hip_runtime.h>

// Nadaraya-Watson kernel regression, one block (256 threads) per row.
// out[i] = sum_j softmax_j(-0.5*((q[i]-K[i,j])*w)^2) * V[i,j]
// All exponents <= 0 so exp() <= 1: no max-subtraction needed -> single pass.
//
// Specialized path: compile-time unroll (ITERS = K/4/256) issues all
// global_load_dwordx4 up front (max memory-level parallelism), with
// non-temporal hint (streaming data, working set > L3).

typedef float floatx4 __attribute__((ext_vector_type(4)));

template <int ITERS>
__global__ __launch_bounds__(256) void nw_regression_unrolled(
    const float* __restrict__ q,
    const float* __restrict__ keys,
    const float* __restrict__ values,
    const float* __restrict__ w,
    float* __restrict__ out,
    int K)
{
    const int row = blockIdx.x;
    const float qi = q[row];
    const float wv = w[0];

    const floatx4* __restrict__ krow =
        reinterpret_cast<const floatx4*>(keys + (size_t)row * (size_t)K);
    const floatx4* __restrict__ vrow =
        reinterpret_cast<const floatx4*>(values + (size_t)row * (size_t)K);

    floatx4 kreg[ITERS];
    floatx4 vreg[ITERS];

    // Issue all loads first: 2*ITERS outstanding 16B loads per thread.
    #pragma unroll
    for (int it = 0; it < ITERS; ++it) {
        kreg[it] = __builtin_nontemporal_load(&krow[threadIdx.x + it * 256]);
        vreg[it] = __builtin_nontemporal_load(&vrow[threadIdx.x + it * 256]);
    }

    float sum_e = 0.0f;
    float sum_ev = 0.0f;

    #pragma unroll
    for (int it = 0; it < ITERS; ++it) {
        floatx4 kv = kreg[it];
        floatx4 vv = vreg[it];
        #pragma unroll
        for (int c = 0; c < 4; ++c) {
            float d = (qi - kv[c]) * wv;
            float e = __expf(-0.5f * d * d);
            sum_e  += e;
            sum_ev += e * vv[c];
        }
    }

    // Wave-level butterfly reduce (wave = 64 lanes on CDNA).
    #pragma unroll
    for (int off = 32; off > 0; off >>= 1) {
        sum_e  += __shfl_down(sum_e, off, 64);
        sum_ev += __shfl_down(sum_ev, off, 64);
    }

    __shared__ float s_e[4];
    __shared__ float s_ev[4];
    const int wid  = threadIdx.x >> 6;
    const int lane = threadIdx.x & 63;
    if (lane == 0) {
        s_e[wid]  = sum_e;
        s_ev[wid] = sum_ev;
    }
    __syncthreads();

    if (threadIdx.x == 0) {
        float te  = (s_e[0] + s_e[1]) + (s_e[2] + s_e[3]);
        float tev = (s_ev[0] + s_ev[1]) + (s_ev[2] + s_ev[3]);
        out[row] = tev / te;
    }
}

// Generic fallback for K not a multiple of 1024.
__global__ __launch_bounds__(256) void nw_regression_generic(
    const float* __restrict__ q,
    const float* __restrict__ keys,
    const float* __restrict__ values,
    const float* __restrict__ w,
    float* __restrict__ out,
    int K)
{
    const int row = blockIdx.x;
    const float qi = q[row];
    const float wv = w[0];

    const float* krow = keys + (size_t)row * (size_t)K;
    const float* vrow = values + (size_t)row * (size_t)K;

    float sum_e = 0.0f;
    float sum_ev = 0.0f;

    for (int j = threadIdx.x; j < K; j += 256) {
        float d = (qi - krow[j]) * wv;
        float e = __expf(-0.5f * d * d);
        sum_e  += e;
        sum_ev += e * vrow[j];
    }

    #pragma unroll
    for (int off = 32; off > 0; off >>= 1) {
        sum_e  += __shfl_down(sum_e, off, 64);
        sum_ev += __shfl_down(sum_ev, off, 64);
    }

    __shared__ float s_e[4];
    __shared__ float s_ev[4];
    const int wid  = threadIdx.x >> 6;
    const int lane = threadIdx.x & 63;
    if (lane == 0) {
        s_e[wid]  = sum_e;
        s_ev[wid] = sum_ev;
    }
    __syncthreads();

    if (threadIdx.x == 0) {
        float te  = (s_e[0] + s_e[1]) + (s_e[2] + s_e[3]);
        float tev = (s_ev[0] + s_ev[1]) + (s_ev[2] + s_ev[3]);
        out[row] = tev / te;
    }
}

extern "C" void kernel_launch(void* const* d_in, const int* in_sizes, int n_in,
                              void* d_out, int out_size, void* d_ws, size_t ws_size,
                              hipStream_t stream) {
    const float* q      = (const float*)d_in[0];
    const float* keys   = (const float*)d_in[1];
    const float* values = (const float*)d_in[2];
    const float* w      = (const float*)d_in[3];
    float* out = (float*)d_out;

    const int N = in_sizes[0];
    const int K = in_sizes[1] / N;

    if (K == 8192) {
        nw_regression_unrolled<8><<<N, 256, 0, stream>>>(q, keys, values, w, out, K);
    } else if (K == 4096) {
        nw_regression_unrolled<4><<<N, 256, 0, stream>>>(q, keys, values, w, out, K);
    } else if (K == 2048) {
        nw_regression_unrolled<2><<<N, 256, 0, stream>>>(q, keys, values, w, out, K);
    } else {
        nw_regression_generic<<<N, 256, 0, stream>>>(q, keys, values, w, out, K);
    }
}

// Round 3
// 79.820 us; speedup vs baseline: 1.1858x; 1.0392x over previous
//
#include <hip/hip_runtime.h>

// Nadaraya-Watson kernel regression, one block per row.
// out[i] = sum_j softmax_j(-0.5*((q[i]-K[i,j])*w)^2) * V[i,j]
// All exponents <= 0 so exp() <= 1: no max-subtraction needed -> single pass.
//
// 512 threads/block, ITERS = K/4/512. All loads issued up front
// (8 outstanding dwordx4 per thread), non-temporal (streaming, > L3).

typedef float floatx4 __attribute__((ext_vector_type(4)));

template <int ITERS, int BLK>
__global__ __launch_bounds__(BLK) void nw_regression_unrolled(
    const float* __restrict__ q,
    const float* __restrict__ keys,
    const float* __restrict__ values,
    const float* __restrict__ w,
    float* __restrict__ out,
    int K)
{
    const int row = blockIdx.x;
    const float qi = q[row];
    const float wv = w[0];

    const floatx4* __restrict__ krow =
        reinterpret_cast<const floatx4*>(keys + (size_t)row * (size_t)K);
    const floatx4* __restrict__ vrow =
        reinterpret_cast<const floatx4*>(values + (size_t)row * (size_t)K);

    floatx4 kreg[ITERS];
    floatx4 vreg[ITERS];

    // Issue all loads first: 2*ITERS outstanding 16B loads per thread.
    #pragma unroll
    for (int it = 0; it < ITERS; ++it) {
        kreg[it] = __builtin_nontemporal_load(&krow[threadIdx.x + it * BLK]);
        vreg[it] = __builtin_nontemporal_load(&vrow[threadIdx.x + it * BLK]);
    }

    float sum_e = 0.0f;
    float sum_ev = 0.0f;

    #pragma unroll
    for (int it = 0; it < ITERS; ++it) {
        floatx4 kv = kreg[it];
        floatx4 vv = vreg[it];
        #pragma unroll
        for (int c = 0; c < 4; ++c) {
            float d = (qi - kv[c]) * wv;
            float e = __expf(-0.5f * d * d);
            sum_e  += e;
            sum_ev += e * vv[c];
        }
    }

    // Wave-level butterfly reduce (wave = 64 lanes on CDNA).
    #pragma unroll
    for (int off = 32; off > 0; off >>= 1) {
        sum_e  += __shfl_down(sum_e, off, 64);
        sum_ev += __shfl_down(sum_ev, off, 64);
    }

    __shared__ float s_e[BLK / 64];
    __shared__ float s_ev[BLK / 64];
    const int wid  = threadIdx.x >> 6;
    const int lane = threadIdx.x & 63;
    if (lane == 0) {
        s_e[wid]  = sum_e;
        s_ev[wid] = sum_ev;
    }
    __syncthreads();

    if (threadIdx.x == 0) {
        float te = 0.0f, tev = 0.0f;
        #pragma unroll
        for (int i = 0; i < BLK / 64; ++i) {
            te  += s_e[i];
            tev += s_ev[i];
        }
        out[row] = tev / te;
    }
}

// Generic fallback for other K.
__global__ __launch_bounds__(256) void nw_regression_generic(
    const float* __restrict__ q,
    const float* __restrict__ keys,
    const float* __restrict__ values,
    const float* __restrict__ w,
    float* __restrict__ out,
    int K)
{
    const int row = blockIdx.x;
    const float qi = q[row];
    const float wv = w[0];

    const float* krow = keys + (size_t)row * (size_t)K;
    const float* vrow = values + (size_t)row * (size_t)K;

    float sum_e = 0.0f;
    float sum_ev = 0.0f;

    for (int j = threadIdx.x; j < K; j += 256) {
        float d = (qi - krow[j]) * wv;
        float e = __expf(-0.5f * d * d);
        sum_e  += e;
        sum_ev += e * vrow[j];
    }

    #pragma unroll
    for (int off = 32; off > 0; off >>= 1) {
        sum_e  += __shfl_down(sum_e, off, 64);
        sum_ev += __shfl_down(sum_ev, off, 64);
    }

    __shared__ float s_e[4];
    __shared__ float s_ev[4];
    const int wid  = threadIdx.x >> 6;
    const int lane = threadIdx.x & 63;
    if (lane == 0) {
        s_e[wid]  = sum_e;
        s_ev[wid] = sum_ev;
    }
    __syncthreads();

    if (threadIdx.x == 0) {
        float te  = (s_e[0] + s_e[1]) + (s_e[2] + s_e[3]);
        float tev = (s_ev[0] + s_ev[1]) + (s_ev[2] + s_ev[3]);
        out[row] = tev / te;
    }
}

extern "C" void kernel_launch(void* const* d_in, const int* in_sizes, int n_in,
                              void* d_out, int out_size, void* d_ws, size_t ws_size,
                              hipStream_t stream) {
    const float* q      = (const float*)d_in[0];
    const float* keys   = (const float*)d_in[1];
    const float* values = (const float*)d_in[2];
    const float* w      = (const float*)d_in[3];
    float* out = (float*)d_out;

    const int N = in_sizes[0];
    const int K = in_sizes[1] / N;

    if (K == 8192) {
        nw_regression_unrolled<4, 512><<<N, 512, 0, stream>>>(q, keys, values, w, out, K);
    } else if (K == 4096) {
        nw_regression_unrolled<2, 512><<<N, 512, 0, stream>>>(q, keys, values, w, out, K);
    } else if (K == 2048) {
        nw_regression_unrolled<2, 256><<<N, 256, 0, stream>>>(q, keys, values, w, out, K);
    } else {
        nw_regression_generic<<<N, 256, 0, stream>>>(q, keys, values, w, out, K);
    }
}